// Round 3
// baseline (655.876 us; speedup 1.0000x reference)
//
#include <hip/hip_runtime.h>
#include <math.h>
#include <float.h>

#define BB 32
#define CC 64
#define KK 8192
#define NPIX 256
#define NELEM (BB*CC*NPIX)  // 524288

struct UpW4 { int i0[16]; float w[16][4]; };

__global__ void k_init(const float* __restrict__ f, float* __restrict__ zr,
                       float* __restrict__ out, int n) {
  int i = blockIdx.x * 256 + threadIdx.x;
  if (i < n) { zr[i] = f[i]; out[i] = 0.f; }
}

__global__ void k_wsq(const float* __restrict__ emb, float* __restrict__ wsq32) {
  int k = blockIdx.x * 256 + threadIdx.x;
  if (k < KK) {
    const float* row = emb + k * 64;
    double s = 0.0;
    #pragma unroll
    for (int c = 0; c < 64; ++c) s += (double)row[c] * (double)row[c];
    wsq32[k] = (float)s;   // within ~1 ulp of np pairwise-f32: argmin-safe
  }
}

// numpy-exact area mean: out[b,c,y,x] = (sum_dy pairwise_sum(dx-row)) / bs^2
// pairwise_sum (numpy loops.c.src): n=16: r[j]=a[j]+a[j+8], tree; n=8: tree;
// n<8: sequential. dy accumulation sequential (nditer reduce).
__global__ void k_down(const float* __restrict__ zr, float* __restrict__ zd, int pn) {
#pragma clang fp contract(off)
  int i = blockIdx.x * 256 + threadIdx.x;
  int pnpn = pn * pn;
  int n = BB * CC * pnpn;
  if (i >= n) return;
  int x = i % pn; int y = (i / pn) % pn; int bc = i / pnpn;
  int bs = 16 / pn;
  const float* src = zr + bc * NPIX + (y * bs) * 16 + x * bs;
  float acc = 0.f;
  for (int dy = 0; dy < bs; ++dy) {
    const float* a = src + dy * 16;
    float s;
    if (bs == 16) {
      float r[8];
      #pragma unroll
      for (int j = 0; j < 8; ++j) r[j] = a[j] + a[8 + j];
      s = ((r[0] + r[1]) + (r[2] + r[3])) + ((r[4] + r[5]) + (r[6] + r[7]));
    } else if (bs == 8) {
      s = ((a[0] + a[1]) + (a[2] + a[3])) + ((a[4] + a[5]) + (a[6] + a[7]));
    } else if (bs == 4) {
      s = ((a[0] + a[1]) + a[2]) + a[3];
    } else {
      s = a[0] + a[1];
    }
    acc = acc + s;
  }
  zd[i] = acc * (1.f / (bs * bs));
}

// One workgroup: 32 vectors x kchunk codes. grid = (numVec/32, KSPLIT)
// Scores replicate numpy-f32 bit-exactly:
//   dot = ascending-c FMA chain from 0 (BLAS sgemm microkernel order)
//   d   = fl( fl(zsq + wsq_k) - fl(2*dot) ), argmin first-index.
__global__ __launch_bounds__(256) void k_argmin(
    const float* __restrict__ zd, const float* __restrict__ emb,
    const float* __restrict__ wsq32,
    float* __restrict__ pd, int* __restrict__ pi,
    int numVec, int pnpn, int kchunk) {
#pragma clang fp contract(off)
  __shared__ __align__(16) float zt[32][68];
  __shared__ __align__(16) float et[64 * 64];
  __shared__ float ws_s[64];
  __shared__ float red_d[256];
  __shared__ int   red_i[256];
  int tid = threadIdx.x;
  int v0 = blockIdx.x * 32;
  int kbase = blockIdx.y * kchunk;

  for (int idx = tid; idx < 32 * 64; idx += 256) {
    int v = idx >> 6, c = idx & 63;
    int vi = v0 + v;
    float val = 0.f;
    if (vi < numVec) {
      int b = vi / pnpn, p = vi % pnpn;
      val = zd[(b * 64 + c) * pnpn + p];
    }
    zt[v][c] = val;
  }
  __syncthreads();

  const int v = tid & 31, kg = tid >> 5;
  float4 z4[16];
  #pragma unroll
  for (int i = 0; i < 16; ++i) z4[i] = *reinterpret_cast<float4*>(&zt[v][i * 4]);
  float zsq = 0.f;   // scheme-free: uniform ulp shift preserves argmin
  #pragma unroll
  for (int i = 0; i < 16; ++i)
    zsq += z4[i].x * z4[i].x + z4[i].y * z4[i].y + z4[i].z * z4[i].z + z4[i].w * z4[i].w;

  float bd = FLT_MAX; int bi = 0x7fffffff;
  for (int k0 = 0; k0 < kchunk; k0 += 64) {
    __syncthreads();
    for (int idx = tid; idx < 64 * 64; idx += 256)
      et[idx] = emb[(kbase + k0) * 64 + idx];
    if (tid < 64) ws_s[tid] = wsq32[kbase + k0 + tid];
    __syncthreads();
    #pragma unroll
    for (int j = 0; j < 8; ++j) {
      int kl = kg * 8 + j;
      const float4* e4 = reinterpret_cast<const float4*>(&et[kl * 64]);
      float acc = 0.f;
      #pragma unroll
      for (int i = 0; i < 16; ++i) {
        float4 e = e4[i];
        acc = __builtin_fmaf(z4[i].x, e.x, acc);
        acc = __builtin_fmaf(z4[i].y, e.y, acc);
        acc = __builtin_fmaf(z4[i].z, e.z, acc);
        acc = __builtin_fmaf(z4[i].w, e.w, acc);
      }
      float t1 = zsq + ws_s[kl];
      float d  = t1 - 2.0f * acc;
      if (d < bd) { bd = d; bi = kbase + k0 + kl; }   // strict <: first index
    }
  }
  red_d[tid] = bd; red_i[tid] = bi;
  __syncthreads();
  if (tid < 32) {
    float fb = red_d[tid]; int fi = red_i[tid];
    #pragma unroll
    for (int g = 1; g < 8; ++g) {
      float cd = red_d[g * 32 + tid]; int ci = red_i[g * 32 + tid];
      if (cd < fb || (cd == fb && ci < fi)) { fb = cd; fi = ci; }
    }
    int vi = v0 + tid;
    if (vi < numVec) {
      pd[blockIdx.y * numVec + vi] = fb;
      pi[blockIdx.y * numVec + vi] = fi;
    }
  }
}

__global__ void k_argmin_reduce(const float* __restrict__ pd, const int* __restrict__ pi,
                                int* __restrict__ tok, int numVec, int ksplit) {
  int vi = blockIdx.x * 256 + threadIdx.x;
  if (vi >= numVec) return;
  float bd = pd[vi]; int bi = pi[vi];
  for (int s = 1; s < ksplit; ++s) {
    float cd = pd[s * numVec + vi]; int ci = pi[s * numVec + vi];
    if (cd < bd || (cd == bd && ci < bi)) { bd = cd; bi = ci; }
  }
  tok[vi] = bi;
}

__global__ void k_upsample(const int* __restrict__ tok, const float* __restrict__ emb,
                           UpW4 W, float* __restrict__ hup, int pn) {
  int i = blockIdx.x * 256 + threadIdx.x;
  if (i >= NELEM) return;
  int p = i & 255; int c = (i >> 8) & 63; int b = i >> 14;
  if (pn == 16) { hup[i] = emb[tok[b * 256 + p] * 64 + c]; return; }
  int y = p >> 4, x = p & 15;
  int pnpn = pn * pn;
  const int* tb = tok + b * pnpn;
  float acc = 0.f;
  #pragma unroll
  for (int ty = 0; ty < 4; ++ty) {
    float wy = W.w[y][ty];
    int iy = W.i0[y] + ty; if (iy > pn - 1) iy = pn - 1;
    float tmp = 0.f;
    #pragma unroll
    for (int tx = 0; tx < 4; ++tx) {
      float wx = W.w[x][tx];
      int ix = W.i0[x] + tx; if (ix > pn - 1) ix = pn - 1;
      tmp += wx * emb[tb[iy * pn + ix] * 64 + c];
    }
    acc += wy * tmp;
  }
  hup[i] = acc;
}

// grid = (B, 8): one batch image x 8 output channels per wg
__global__ __launch_bounds__(256) void k_conv(
    const float* __restrict__ hup, const float* __restrict__ w,
    const float* __restrict__ bias, float* __restrict__ out, float* __restrict__ zr) {
  __shared__ float ins[64][NPIX];
  __shared__ float wsh[8 * 64 * 9];
  int tid = threadIdx.x;
  int b = blockIdx.x;
  int ocb = blockIdx.y;
  for (int c = 0; c < 64; ++c)
    ins[c][tid] = hup[(b * 64 + c) * NPIX + tid];
  for (int idx = tid; idx < 8 * 64 * 9; idx += 256)
    wsh[idx] = w[ocb * 8 * 64 * 9 + idx];
  __syncthreads();
  int y = tid >> 4, x = tid & 15;
  float acc[8];
  #pragma unroll
  for (int j = 0; j < 8; ++j) acc[j] = bias[ocb * 8 + j];
  for (int ic = 0; ic < 64; ++ic) {
    float vtap[9];
    #pragma unroll
    for (int dy = 0; dy < 3; ++dy)
      #pragma unroll
      for (int dx = 0; dx < 3; ++dx) {
        int yy = y + dy - 1, xx = x + dx - 1;
        vtap[dy * 3 + dx] = (yy >= 0 && yy < 16 && xx >= 0 && xx < 16)
                            ? ins[ic][yy * 16 + xx] : 0.f;
      }
    #pragma unroll
    for (int j = 0; j < 8; ++j) {
      const float* wp = &wsh[(j * 64 + ic) * 9];
      float a = acc[j];
      #pragma unroll
      for (int t = 0; t < 9; ++t) a += vtap[t] * wp[t];
      acc[j] = a;
    }
  }
  #pragma unroll
  for (int j = 0; j < 8; ++j) {
    int oc = ocb * 8 + j;
    float h = ins[oc][tid];
    float ho = 0.5f * h + 0.5f * acc[j];
    int gi = (b * 64 + oc) * NPIX + tid;
    out[gi] += ho;
    zr[gi]  -= ho;
  }
}

extern "C" void kernel_launch(void* const* d_in, const int* in_sizes, int n_in,
                              void* d_out, int out_size, void* d_ws, size_t ws_size,
                              hipStream_t stream) {
  const float* f    = (const float*)d_in[0];
  const float* emb  = (const float*)d_in[1];
  const float* phiw = (const float*)d_in[2];
  const float* phib = (const float*)d_in[3];
  float* out = (float*)d_out;

  float* ws  = (float*)d_ws;
  float* zr    = ws;                       // 524288
  float* zd    = ws + 524288;              // 524288
  float* hup   = ws + 1048576;             // 524288
  float* wsq32 = ws + 1572864;             // 8192
  int*   tok   = (int*)(ws + 1581056);     // 8192
  float* pd    = ws + 1589248;             // 32768
  int*   pi    = (int*)(ws + 1622016);     // 32768

  // --- PHI_IDX: replicate numpy linspace + argmin in doubles ---
  double start = 1.0 / 3.0 / 4.0;
  double stop  = 1.0 - 1.0 / 3.0 / 4.0;
  double step  = (stop - start) / 3.0;
  double ticks[4] = { start, 1.0 * step + start, 2.0 * step + start, stop };
  int phi_idx[5];
  for (int si = 0; si < 5; ++si) {
    double xx = si / 4.0;
    int bj = 0; double bdd = fabs(ticks[0] - xx);
    for (int j = 1; j < 4; ++j) { double dd = fabs(ticks[j] - xx); if (dd < bdd) { bdd = dd; bj = j; } }
    phi_idx[si] = bj;
  }

  // --- cubic (Keys a=-0.5) resize weights, column-normalized like jax ---
  static const int MSarr[5] = {1, 2, 4, 8, 16};
  UpW4 Wmat[4];
  for (int si = 0; si < 4; ++si) {
    int n = MSarr[si];
    for (int o = 0; o < 16; ++o) {
      double s = (o + 0.5) * (n / 16.0) - 0.5;
      double wv[8]; double wsum = 0.0;
      for (int ii = 0; ii < n; ++ii) {
        double xx = fabs(s - ii);
        double val;
        if (xx >= 2.0) val = 0.0;
        else if (xx >= 1.0) val = ((-0.5 * xx + 2.5) * xx - 4.0) * xx + 2.0;
        else val = ((1.5 * xx - 2.5) * xx) * xx + 1.0;
        wv[ii] = val; wsum += val;
      }
      int i0 = 0;
      while (i0 < n && wv[i0] == 0.0) ++i0;
      if (i0 + 4 > n) i0 = (n >= 4) ? n - 4 : 0;
      Wmat[si].i0[o] = i0;
      for (int t = 0; t < 4; ++t)
        Wmat[si].w[o][t] = (i0 + t < n) ? (float)(wv[i0 + t] / wsum) : 0.f;
    }
  }

  k_init<<<NELEM / 256, 256, 0, stream>>>(f, zr, out, NELEM);
  k_wsq<<<KK / 256, 256, 0, stream>>>(emb, wsq32);

  const int KS[5] = {128, 32, 16, 8, 4};
  for (int si = 0; si < 5; ++si) {
    int pn = MSarr[si], pnpn = pn * pn, numVec = BB * pnpn;
    const float* zsrc;
    if (si < 4) {
      int n = BB * CC * pnpn;
      k_down<<<(n + 255) / 256, 256, 0, stream>>>(zr, zd, pn);
      zsrc = zd;
    } else {
      zsrc = zr;
    }
    int ksplit = KS[si], kchunk = KK / ksplit;
    dim3 g(numVec / 32, ksplit);
    k_argmin<<<g, 256, 0, stream>>>(zsrc, emb, wsq32, pd, pi, numVec, pnpn, kchunk);
    k_argmin_reduce<<<(numVec + 255) / 256, 256, 0, stream>>>(pd, pi, tok, numVec, ksplit);
    k_upsample<<<NELEM / 256, 256, 0, stream>>>(tok, emb, Wmat[si < 4 ? si : 0], hup, pn);
    int pidx = phi_idx[si];
    k_conv<<<dim3(BB, 8), 256, 0, stream>>>(hup, phiw + pidx * 64 * 64 * 9,
                                            phib + pidx * 64, out, zr);
  }
}

// Round 4
// 608.695 us; speedup vs baseline: 1.0775x; 1.0775x over previous
//
#include <hip/hip_runtime.h>
#include <math.h>
#include <float.h>

#define BB 32
#define CC 64
#define KK 8192
#define NPIX 256
#define NELEM (BB*CC*NPIX)  // 524288

__global__ void k_init(const float* __restrict__ f, float* __restrict__ zr,
                       float* __restrict__ out, int n) {
  int i = blockIdx.x * 256 + threadIdx.x;
  if (i < n) { zr[i] = f[i]; out[i] = 0.f; }
}

__global__ void k_wsq(const float* __restrict__ emb, float* __restrict__ wsq32) {
  int k = blockIdx.x * 256 + threadIdx.x;
  if (k < KK) {
    const float* row = emb + k * 64;
    double s = 0.0;
    #pragma unroll
    for (int c = 0; c < 64; ++c) s += (double)row[c] * (double)row[c];
    wsq32[k] = (float)s;   // within ~1 ulp of np pairwise-f32: argmin-safe
  }
}

// numpy-exact area mean: pairwise row sum (n=16: fold8+tree; n=8: tree; n<8 seq),
// sequential dy accumulation, * exact pow2 scale.
__global__ void k_down(const float* __restrict__ zr, float* __restrict__ zd, int pn) {
#pragma clang fp contract(off)
  int i = blockIdx.x * 256 + threadIdx.x;
  int pnpn = pn * pn;
  int n = BB * CC * pnpn;
  if (i >= n) return;
  int x = i % pn; int y = (i / pn) % pn; int bc = i / pnpn;
  int bs = 16 / pn;
  const float* src = zr + bc * NPIX + (y * bs) * 16 + x * bs;
  float acc = 0.f;
  for (int dy = 0; dy < bs; ++dy) {
    const float* a = src + dy * 16;
    float s;
    if (bs == 16) {
      float r[8];
      #pragma unroll
      for (int j = 0; j < 8; ++j) r[j] = a[j] + a[8 + j];
      s = ((r[0] + r[1]) + (r[2] + r[3])) + ((r[4] + r[5]) + (r[6] + r[7]));
    } else if (bs == 8) {
      s = ((a[0] + a[1]) + (a[2] + a[3])) + ((a[4] + a[5]) + (a[6] + a[7]));
    } else if (bs == 4) {
      s = ((a[0] + a[1]) + a[2]) + a[3];
    } else {
      s = a[0] + a[1];
    }
    acc = acc + s;
  }
  zd[i] = acc * (1.f / (bs * bs));
}

// One workgroup: 32 vectors x kchunk codes. grid = (numVec/32, KSPLIT)
// Exact numpy-f32 score: ascending-c FMA chain; d = fl(fl(zsq+wsq) - 2*dot).
// __launch_bounds__(256,4): 128-VGPR budget so z4[16] (64 VGPRs) stays in regs.
__global__ __launch_bounds__(256, 4) void k_argmin(
    const float* __restrict__ zd, const float* __restrict__ emb,
    const float* __restrict__ wsq32,
    float* __restrict__ pd, int* __restrict__ pi,
    int numVec, int pnpn, int kchunk) {
#pragma clang fp contract(off)
  __shared__ __align__(16) float zt[32][68];
  __shared__ __align__(16) float et[64 * 64];
  __shared__ float ws_s[64];
  __shared__ float red_d[256];
  __shared__ int   red_i[256];
  int tid = threadIdx.x;
  int v0 = blockIdx.x * 32;
  int kbase = blockIdx.y * kchunk;

  for (int idx = tid; idx < 32 * 64; idx += 256) {
    int v = idx >> 6, c = idx & 63;
    int vi = v0 + v;
    float val = 0.f;
    if (vi < numVec) {
      int b = vi / pnpn, p = vi % pnpn;
      val = zd[(b * 64 + c) * pnpn + p];
    }
    zt[v][c] = val;
  }
  __syncthreads();

  const int v = tid & 31, kg = tid >> 5;
  float4 z4[16];
  #pragma unroll
  for (int i = 0; i < 16; ++i) z4[i] = *reinterpret_cast<float4*>(&zt[v][i * 4]);
  float zsq = 0.f;   // scheme-free: uniform ulp shift preserves argmin
  #pragma unroll
  for (int i = 0; i < 16; ++i)
    zsq += z4[i].x * z4[i].x + z4[i].y * z4[i].y + z4[i].z * z4[i].z + z4[i].w * z4[i].w;

  float bd = FLT_MAX; int bi = 0x7fffffff;
  for (int k0 = 0; k0 < kchunk; k0 += 64) {
    __syncthreads();
    {
      const float4* gsrc = reinterpret_cast<const float4*>(emb + (size_t)(kbase + k0) * 64);
      float4* ldst = reinterpret_cast<float4*>(et);
      #pragma unroll
      for (int idx = 0; idx < 4; ++idx)
        ldst[tid + idx * 256] = gsrc[tid + idx * 256];
    }
    if (tid < 64) ws_s[tid] = wsq32[kbase + k0 + tid];
    __syncthreads();
    #pragma unroll
    for (int j = 0; j < 8; ++j) {
      int kl = kg * 8 + j;
      const float4* e4 = reinterpret_cast<const float4*>(&et[kl * 64]);
      float acc = 0.f;
      #pragma unroll
      for (int i = 0; i < 16; ++i) {
        float4 e = e4[i];
        acc = __builtin_fmaf(z4[i].x, e.x, acc);
        acc = __builtin_fmaf(z4[i].y, e.y, acc);
        acc = __builtin_fmaf(z4[i].z, e.z, acc);
        acc = __builtin_fmaf(z4[i].w, e.w, acc);
      }
      float t1 = zsq + ws_s[kl];
      float d  = t1 - 2.0f * acc;
      if (d < bd) { bd = d; bi = kbase + k0 + kl; }   // strict <: first index
    }
  }
  red_d[tid] = bd; red_i[tid] = bi;
  __syncthreads();
  if (tid < 32) {
    float fb = red_d[tid]; int fi = red_i[tid];
    #pragma unroll
    for (int g = 1; g < 8; ++g) {
      float cd = red_d[g * 32 + tid]; int ci = red_i[g * 32 + tid];
      if (cd < fb || (cd == fb && ci < fi)) { fb = cd; fi = ci; }
    }
    int vi = v0 + tid;
    if (vi < numVec) {
      pd[blockIdx.y * numVec + vi] = fb;
      pi[blockIdx.y * numVec + vi] = fi;
    }
  }
}

__global__ void k_argmin_reduce(const float* __restrict__ pd, const int* __restrict__ pi,
                                int* __restrict__ tok, int numVec, int ksplit) {
  int vi = blockIdx.x * 256 + threadIdx.x;
  if (vi >= numVec) return;
  float bd = pd[vi]; int bi = pi[vi];
  for (int s = 1; s < ksplit; ++s) {
    float cd = pd[s * numVec + vi]; int ci = pi[s * numVec + vi];
    if (cd < bd || (cd == bd && ci < bi)) { bd = cd; bi = ci; }
  }
  tok[vi] = bi;
}

// Cubic (Keys a=-0.5) weights computed IN-KERNEL (f64, bit-identical to the
// host/double formula; window-sum == full-row sum since out-of-window taps are
// exact zeros). Stored in LDS -> no per-lane scratch-indexed kernarg struct.
__global__ __launch_bounds__(256) void k_upsample(
    const int* __restrict__ tok, const float* __restrict__ emb,
    float* __restrict__ hup, int pn) {
  int i = blockIdx.x * 256 + threadIdx.x;
  int p = i & 255; int c = (i >> 8) & 63; int b = i >> 14;
  if (pn == 16) { hup[i] = emb[tok[b * 256 + p] * 64 + c]; return; }

  __shared__ float wsh[16][4];
  __shared__ int   i0sh[16];
  int tid = threadIdx.x;
  if (tid < 16) {
    double s = (tid + 0.5) * ((double)pn / 16.0) - 0.5;
    int i0 = (int)floor(s) - 1;
    int hi = pn - 4; if (hi < 0) hi = 0;
    if (i0 < 0) i0 = 0; if (i0 > hi) i0 = hi;
    double wv[4]; double sum = 0.0;
    #pragma unroll
    for (int t = 0; t < 4; ++t) {
      int ii = i0 + t;
      double w = 0.0;
      if (ii < pn) {
        double xx = fabs(s - (double)ii);
        if (xx < 1.0)       w = ((1.5 * xx - 2.5) * xx) * xx + 1.0;
        else if (xx < 2.0)  w = ((-0.5 * xx + 2.5) * xx - 4.0) * xx + 2.0;
      }
      wv[t] = w; sum += w;
    }
    i0sh[tid] = i0;
    #pragma unroll
    for (int t = 0; t < 4; ++t) wsh[tid][t] = (float)(wv[t] / sum);
  }
  __syncthreads();

  int y = p >> 4, x = p & 15;
  int pnpn = pn * pn;
  const int* tb = tok + b * pnpn;
  int iy0 = i0sh[y], ix0 = i0sh[x];
  float acc = 0.f;
  #pragma unroll
  for (int ty = 0; ty < 4; ++ty) {
    float wy = wsh[y][ty];
    int iy = iy0 + ty; if (iy > pn - 1) iy = pn - 1;  // zero-weight taps: clamp keeps reads in-bounds
    float tmp = 0.f;
    #pragma unroll
    for (int tx = 0; tx < 4; ++tx) {
      float wx = wsh[x][tx];
      int ix = ix0 + tx; if (ix > pn - 1) ix = pn - 1;
      tmp += wx * emb[tb[iy * pn + ix] * 64 + c];
    }
    acc += wy * tmp;
  }
  hup[i] = acc;
}

// grid = (B, 8): one batch image x 8 output channels per wg
__global__ __launch_bounds__(256) void k_conv(
    const float* __restrict__ hup, const float* __restrict__ w,
    const float* __restrict__ bias, float* __restrict__ out, float* __restrict__ zr) {
  __shared__ float ins[64][NPIX];
  __shared__ float wsh[8 * 64 * 9];
  int tid = threadIdx.x;
  int b = blockIdx.x;
  int ocb = blockIdx.y;
  for (int c = 0; c < 64; ++c)
    ins[c][tid] = hup[(b * 64 + c) * NPIX + tid];
  for (int idx = tid; idx < 8 * 64 * 9; idx += 256)
    wsh[idx] = w[ocb * 8 * 64 * 9 + idx];
  __syncthreads();
  int y = tid >> 4, x = tid & 15;
  float acc[8];
  #pragma unroll
  for (int j = 0; j < 8; ++j) acc[j] = bias[ocb * 8 + j];
  for (int ic = 0; ic < 64; ++ic) {
    float vtap[9];
    #pragma unroll
    for (int dy = 0; dy < 3; ++dy)
      #pragma unroll
      for (int dx = 0; dx < 3; ++dx) {
        int yy = y + dy - 1, xx = x + dx - 1;
        vtap[dy * 3 + dx] = (yy >= 0 && yy < 16 && xx >= 0 && xx < 16)
                            ? ins[ic][yy * 16 + xx] : 0.f;
      }
    #pragma unroll
    for (int j = 0; j < 8; ++j) {
      const float* wp = &wsh[(j * 64 + ic) * 9];
      float a = acc[j];
      #pragma unroll
      for (int t = 0; t < 9; ++t) a += vtap[t] * wp[t];
      acc[j] = a;
    }
  }
  #pragma unroll
  for (int j = 0; j < 8; ++j) {
    int oc = ocb * 8 + j;
    float h = ins[oc][tid];
    float ho = 0.5f * h + 0.5f * acc[j];
    int gi = (b * 64 + oc) * NPIX + tid;
    out[gi] += ho;
    zr[gi]  -= ho;
  }
}

extern "C" void kernel_launch(void* const* d_in, const int* in_sizes, int n_in,
                              void* d_out, int out_size, void* d_ws, size_t ws_size,
                              hipStream_t stream) {
  const float* f    = (const float*)d_in[0];
  const float* emb  = (const float*)d_in[1];
  const float* phiw = (const float*)d_in[2];
  const float* phib = (const float*)d_in[3];
  float* out = (float*)d_out;

  float* ws  = (float*)d_ws;
  float* zr    = ws;                       // 524288
  float* zd    = ws + 524288;              // 524288
  float* hup   = ws + 1048576;             // 524288
  float* wsq32 = ws + 1572864;             // 8192
  int*   tok   = (int*)(ws + 1581056);     // 8192
  float* pd    = ws + 1589248;             // 32768
  int*   pi    = (int*)(ws + 1622016);     // 32768

  // --- PHI_IDX: replicate numpy linspace + argmin in doubles ---
  double start = 1.0 / 3.0 / 4.0;
  double stop  = 1.0 - 1.0 / 3.0 / 4.0;
  double step  = (stop - start) / 3.0;
  double ticks[4] = { start, 1.0 * step + start, 2.0 * step + start, stop };
  int phi_idx[5];
  for (int si = 0; si < 5; ++si) {
    double xx = si / 4.0;
    int bj = 0; double bdd = fabs(ticks[0] - xx);
    for (int j = 1; j < 4; ++j) { double dd = fabs(ticks[j] - xx); if (dd < bdd) { bdd = dd; bj = j; } }
    phi_idx[si] = bj;
  }

  static const int MSarr[5] = {1, 2, 4, 8, 16};

  k_init<<<NELEM / 256, 256, 0, stream>>>(f, zr, out, NELEM);
  k_wsq<<<KK / 256, 256, 0, stream>>>(emb, wsq32);

  const int KS[5] = {128, 32, 16, 8, 4};
  for (int si = 0; si < 5; ++si) {
    int pn = MSarr[si], pnpn = pn * pn, numVec = BB * pnpn;
    const float* zsrc;
    if (si < 4) {
      int n = BB * CC * pnpn;
      k_down<<<(n + 255) / 256, 256, 0, stream>>>(zr, zd, pn);
      zsrc = zd;
    } else {
      zsrc = zr;
    }
    int ksplit = KS[si], kchunk = KK / ksplit;
    dim3 g(numVec / 32, ksplit);
    k_argmin<<<g, 256, 0, stream>>>(zsrc, emb, wsq32, pd, pi, numVec, pnpn, kchunk);
    k_argmin_reduce<<<(numVec + 255) / 256, 256, 0, stream>>>(pd, pi, tok, numVec, ksplit);
    k_upsample<<<NELEM / 256, 256, 0, stream>>>(tok, emb, hup, pn);
    int pidx = phi_idx[si];
    k_conv<<<dim3(BB, 8), 256, 0, stream>>>(hup, phiw + pidx * 64 * 64 * 9,
                                            phib + pidx * 64, out, zr);
  }
}